// Round 4
// baseline (701.461 us; speedup 1.0000x reference)
//
#include <hip/hip_runtime.h>
#include <hip/hip_bf16.h>

// Problem constants
#define NB   8      // batch
#define NH   252    // height
#define NW   192    // width
#define NC   64     // channels
#define HHD  84     // hh = H/3
#define WWD  64     // ww = W/3
#define NE   192    // embed
#define NO   486    // K^4 * HEADS
#define NWIN (NB*HHD*WWD)   // 43008 windows
#define NM   (NWIN*9)       // 387072 rows
#define SCALE_F 0.17677669529663687f  // 32^-0.5

typedef __bf16 bf16x8 __attribute__((ext_vector_type(8)));
typedef float floatx4 __attribute__((ext_vector_type(4)));

// out_w transposed to bf16 [n][k] — static device global, rewritten every call.
__device__ __hip_bfloat16 g_owT[NE * NE];

// ---------------------------------------------------------------------------
// Kernel A: fused window attention. Inputs fp32; writes attention output
// (pre-projection) as bf16 into out_pre (d_ws; B,H,W,192).
// Per block: 8 windows. LDS: 24576 + 2048 + 15616 = 42240 B.
// ---------------------------------------------------------------------------
__global__ __launch_bounds__(256) void ka_window(
    const float* __restrict__ x,
    const float* __restrict__ v_w,
    const float* __restrict__ attn_w,
    const float* __restrict__ attn_b,
    __hip_bfloat16* __restrict__ out_pre)
{
    __shared__ __attribute__((aligned(16))) float xw[8][64][12];   // [win][c][q], q padded 9->12
    __shared__ float pooled[8][64];
    __shared__ float attnS[8][488];                                 // logits -> probs

    const int tid = threadIdx.x;
    const int wbase = blockIdx.x * 8;

    // --- Phase 1: load x windows into LDS (coalesced on c) ---
    #pragma unroll
    for (int it = 0; it < 18; ++it) {
        int t = it * 256 + tid;              // 0..4607
        int win = t / 576;
        int r = t - win * 576;
        int q = r >> 6;                      // pixel in window 0..8
        int c = r & 63;
        int widx = wbase + win;
        int b = widx / 5376;
        int rem = widx - b * 5376;
        int i = rem >> 6;
        int j = rem & 63;
        int pr = q / 3;
        int pc = q - pr * 3;
        int row = i * 3 + pr;
        int col = j * 3 + pc;
        xw[win][c][q] = x[((b * NH + row) * NW + col) * NC + c];
    }
    __syncthreads();

    // --- Phase 1.5: pooled = mean over 9 pixels ---
    #pragma unroll
    for (int it = 0; it < 2; ++it) {
        int t = it * 256 + tid;              // 0..511
        int win = t >> 6;
        int c = t & 63;
        const float* xr = &xw[win][c][0];
        float s = 0.f;
        #pragma unroll
        for (int q = 0; q < 9; ++q) s += xr[q];
        pooled[win][c] = s * (1.f / 9.f);
    }
    __syncthreads();

    // --- Phase 2: logits = (pooled @ attn_w + b) * SCALE ---
    {
        float a0[8], a1[8];
        #pragma unroll
        for (int g = 0; g < 8; ++g) { a0[g] = 0.f; a1[g] = 0.f; }
        const int o0 = tid;                  // < 486 always (tid<256)
        const int o1 = tid + 256;
        const bool has1 = (o1 < NO);
        for (int c = 0; c < 64; ++c) {
            float w0 = attn_w[c * NO + o0];
            float w1 = has1 ? attn_w[c * NO + o1] : 0.f;
            #pragma unroll
            for (int g = 0; g < 8; ++g) {
                float p = pooled[g][c];
                a0[g] = fmaf(p, w0, a0[g]);
                a1[g] = fmaf(p, w1, a1[g]);
            }
        }
        float b0 = attn_b[o0];
        #pragma unroll
        for (int g = 0; g < 8; ++g) attnS[g][o0] = (a0[g] + b0) * SCALE_F;
        if (has1) {
            float b1 = attn_b[o1];
            #pragma unroll
            for (int g = 0; g < 8; ++g) attnS[g][o1] = (a1[g] + b1) * SCALE_F;
        }
    }
    __syncthreads();

    // --- Phase 3: softmax over each group of 9 (8 win * 54 groups = 432) ---
    #pragma unroll
    for (int it = 0; it < 2; ++it) {
        int t = it * 256 + tid;
        if (t < 432) {
            int win = t / 54;
            int g = t - win * 54;
            float* a = &attnS[win][g * 9];
            float m = a[0];
            #pragma unroll
            for (int q = 1; q < 9; ++q) m = fmaxf(m, a[q]);
            float e[9];
            float s = 0.f;
            #pragma unroll
            for (int q = 0; q < 9; ++q) { e[q] = __expf(a[q] - m); s += e[q]; }
            float inv = 1.f / s;
            #pragma unroll
            for (int q = 0; q < 9; ++q) a[q] = e[q] * inv;
        }
    }
    __syncthreads();

    // --- Phase 4: v = x @ v_w (per window), out = attn @ v, scatter ---
    #pragma unroll
    for (int pass = 0; pass < 2; ++pass) {
        int t = pass * 256 + tid;
        if (t < 384) {
            int win = t / 48;
            int e0 = t - win * 48;
            float v0[9], v1[9], v2[9], v3[9];
            #pragma unroll
            for (int q = 0; q < 9; ++q) { v0[q] = 0.f; v1[q] = 0.f; v2[q] = 0.f; v3[q] = 0.f; }
            for (int c = 0; c < 64; ++c) {
                const float* xr = &xw[win][c][0];
                float4 xa = *(const float4*)xr;
                float4 xb = *(const float4*)(xr + 4);
                float x8 = xr[8];
                float xq[9] = {xa.x, xa.y, xa.z, xa.w, xb.x, xb.y, xb.z, xb.w, x8};
                float w0 = v_w[c * NE + e0];
                float w1 = v_w[c * NE + e0 + 48];
                float w2 = v_w[c * NE + e0 + 96];
                float w3 = v_w[c * NE + e0 + 144];
                #pragma unroll
                for (int q = 0; q < 9; ++q) {
                    v0[q] = fmaf(xq[q], w0, v0[q]);
                    v1[q] = fmaf(xq[q], w1, v1[q]);
                    v2[q] = fmaf(xq[q], w2, v2[q]);
                    v3[q] = fmaf(xq[q], w3, v3[q]);
                }
            }
            int widx = wbase + win;
            int b = widx / 5376;
            int rem = widx - b * 5376;
            int i = rem >> 6;
            int j = rem & 63;
            const float* at = &attnS[win][0];
            const int h0 = (e0) >> 5;          // 0..1
            const int h1 = (e0 + 48) >> 5;     // 1..2
            const int h2 = (e0 + 96) >> 5;     // 3..4
            const int h3 = (e0 + 144) >> 5;    // 4..5
            #pragma unroll
            for (int p = 0; p < 9; ++p) {
                const float* r0 = at + h0 * 81 + p * 9;
                const float* r1 = at + h1 * 81 + p * 9;
                const float* r2 = at + h2 * 81 + p * 9;
                const float* r3 = at + h3 * 81 + p * 9;
                float o0 = 0.f, o1 = 0.f, o2 = 0.f, o3 = 0.f;
                #pragma unroll
                for (int q = 0; q < 9; ++q) {
                    o0 = fmaf(r0[q], v0[q], o0);
                    o1 = fmaf(r1[q], v1[q], o1);
                    o2 = fmaf(r2[q], v2[q], o2);
                    o3 = fmaf(r3[q], v3[q], o3);
                }
                int pr = p / 3;
                int pc = p - pr * 3;
                int row = i * 3 + pr;
                int col = j * 3 + pc;
                int base = ((b * NH + row) * NW + col) * NE;
                out_pre[base + e0]       = __float2bfloat16(o0);
                out_pre[base + e0 + 48]  = __float2bfloat16(o1);
                out_pre[base + e0 + 96]  = __float2bfloat16(o2);
                out_pre[base + e0 + 144] = __float2bfloat16(o3);
            }
        }
    }
}

// ---------------------------------------------------------------------------
// Kernel T: transpose out_w (fp32 [k][n]) -> g_owT (bf16 [n][k]), 192x192.
// ---------------------------------------------------------------------------
__global__ __launch_bounds__(256) void kt_transpose(const float* __restrict__ ow)
{
    int idx = blockIdx.x * 256 + threadIdx.x;   // 0..36863
    int n = idx / 192;
    int k = idx - n * 192;
    g_owT[n * 192 + k] = __float2bfloat16(ow[k * 192 + n]);
}

// ---------------------------------------------------------------------------
// Kernel B: final = out_pre @ out_w + out_b  (M=387072, N=K=192), fp32 OUT.
// As-only LDS (25.6 KB); B fragments from L2-resident g_owT (bf16 [n][k]).
// Wave tile: 64 rows x 48 cols -> acc[4][3].
// ---------------------------------------------------------------------------
__global__ __launch_bounds__(256) void kb_gemm(
    const __hip_bfloat16* __restrict__ Ain,
    const float* __restrict__ out_b,
    float* __restrict__ out)
{
    __shared__ __attribute__((aligned(16))) ushort As[64 * 200];   // [m][k], pad 192->200

    const int tid = threadIdx.x;
    const int lane = tid & 63;
    const int wv = tid >> 6;          // wave 0..3 -> n-strip [wv*48, wv*48+48)
    const int m16 = lane & 15;
    const int quad = lane >> 4;

    float bias[3];
    #pragma unroll
    for (int nt = 0; nt < 3; ++nt) bias[nt] = out_b[wv * 48 + nt * 16 + m16];

    const ushort* Au = (const ushort*)Ain;
    const ushort* Bu = (const ushort*)g_owT;

    for (int tI = 0; tI < 8; ++tI) {
        int mbase = (blockIdx.x * 8 + tI) * 64;
        __syncthreads();   // As reuse guard
        #pragma unroll
        for (int it = 0; it < 6; ++it) {
            int chunk = it * 256 + tid;      // 1536 chunks of 16B
            int r = chunk / 24;
            int pos = chunk - r * 24;
            uint4 vdat = *(const uint4*)(Au + (mbase + r) * 192 + pos * 8);
            *(uint4*)(&As[r * 200 + pos * 8]) = vdat;
        }
        __syncthreads();

        floatx4 acc[4][3];
        #pragma unroll
        for (int mt = 0; mt < 4; ++mt)
            #pragma unroll
            for (int nt = 0; nt < 3; ++nt) {
                acc[mt][nt][0] = 0.f; acc[mt][nt][1] = 0.f;
                acc[mt][nt][2] = 0.f; acc[mt][nt][3] = 0.f;
            }

        #pragma unroll
        for (int ks = 0; ks < 6; ++ks) {
            bf16x8 bfrag[3];
            #pragma unroll
            for (int nt = 0; nt < 3; ++nt)
                bfrag[nt] = *(const bf16x8*)(Bu + (wv * 48 + nt * 16 + m16) * 192 + ks * 32 + quad * 8);
            #pragma unroll
            for (int mt = 0; mt < 4; ++mt) {
                bf16x8 afrag = *(const bf16x8*)(&As[(mt * 16 + m16) * 200 + ks * 32 + quad * 8]);
                #pragma unroll
                for (int nt = 0; nt < 3; ++nt)
                    acc[mt][nt] = __builtin_amdgcn_mfma_f32_16x16x32_bf16(afrag, bfrag[nt], acc[mt][nt], 0, 0, 0);
            }
        }

        // Epilogue: C/D layout col=lane&15, row=quad*4+reg; fp32 stores.
        #pragma unroll
        for (int mt = 0; mt < 4; ++mt)
            #pragma unroll
            for (int nt = 0; nt < 3; ++nt)
                #pragma unroll
                for (int r = 0; r < 4; ++r) {
                    int row = mbase + mt * 16 + quad * 4 + r;
                    int col = wv * 48 + nt * 16 + m16;
                    out[row * NE + col] = acc[mt][nt][r] + bias[nt];
                }
    }
}

extern "C" void kernel_launch(void* const* d_in, const int* in_sizes, int n_in,
                              void* d_out, int out_size, void* d_ws, size_t ws_size,
                              hipStream_t stream)
{
    const float* x      = (const float*)d_in[0];
    const float* v_w    = (const float*)d_in[1];
    const float* attn_w = (const float*)d_in[2];
    const float* attn_b = (const float*)d_in[3];
    const float* out_w  = (const float*)d_in[4];
    const float* out_b  = (const float*)d_in[5];
    float* out = (float*)d_out;                       // fp32 output per reference

    __hip_bfloat16* out_pre = (__hip_bfloat16*)d_ws;  // 148,635,648 B (ws-backed, proven ok)

    hipLaunchKernelGGL(ka_window, dim3(NWIN / 8), dim3(256), 0, stream,
                       x, v_w, attn_w, attn_b, out_pre);
    hipLaunchKernelGGL(kt_transpose, dim3(144), dim3(256), 0, stream, out_w);
    hipLaunchKernelGGL(kb_gemm, dim3(NM / 64 / 8), dim3(256), 0, stream,
                       out_pre, out_b, out);
}

// Round 5
// 582.623 us; speedup vs baseline: 1.2040x; 1.2040x over previous
//
#include <hip/hip_runtime.h>
#include <hip/hip_bf16.h>

// Problem constants
#define NB   8      // batch
#define NH   252    // height
#define NW   192    // width
#define NC   64     // channels
#define HHD  84     // hh = H/3
#define WWD  64     // ww = W/3
#define NE   192    // embed
#define NO   486    // K^4 * HEADS
#define NWIN (NB*HHD*WWD)   // 43008 windows
#define NM   (NWIN*9)       // 387072 rows
#define SCALE_F 0.17677669529663687f  // 32^-0.5

typedef __bf16 bf16x8 __attribute__((ext_vector_type(8)));
typedef float floatx4 __attribute__((ext_vector_type(4)));

// Weights pre-transposed to bf16 [n][k] — static device globals, rewritten every call.
__device__ __attribute__((aligned(16))) __hip_bfloat16 g_owT[NE * NE];  // out_w^T [192][192]
__device__ __attribute__((aligned(16))) __hip_bfloat16 g_vwT[NE * NC];  // v_w^T   [192][64]

__device__ __forceinline__ float bfu2f(__bf16 v) { return (float)v; }

// ---------------------------------------------------------------------------
// Kernel T: transpose out_w (fp32 [k][n] 192x192) -> g_owT (bf16 [n][k]) and
// v_w (fp32 [k][n] 64x192) -> g_vwT (bf16 [n][k] 192x64).
// ---------------------------------------------------------------------------
__global__ __launch_bounds__(256) void kt_transpose(
    const float* __restrict__ ow, const float* __restrict__ vw)
{
    int t = blockIdx.x * 256 + threadIdx.x;     // 0..49151
    if (t < 36864) {
        int n = t / 192;
        int k = t - n * 192;
        g_owT[n * 192 + k] = __float2bfloat16(ow[k * 192 + n]);
    } else {
        int tt = t - 36864;                     // 0..12287
        int n = tt / 64;
        int k = tt - n * 64;
        g_vwT[n * 64 + k] = __float2bfloat16(vw[k * 192 + n]);
    }
}

// ---------------------------------------------------------------------------
// Kernel A: fused window attention, MFMA v-GEMM.
// Per block: 8 windows = 72 pixel rows.
//   ph1: x -> bf16 xw[row][k] (A-fragment layout, stride 72 -> conflict-free)
//   ph1.5: pooled (mean of 9 rows)
//   ph2: logits = pooled @ attn_w (fp32 VALU, attn_w from L2)
//   ph3: softmax groups of 9
//   ph4a: v = xw @ v_w via MFMA (B-frags from g_vwT), -> vS LDS bf16
//   ph4b: out = attn @ v (VALU) -> out_pre bf16 scatter
// LDS: 11520 + 32000 + 2048 + 15616 = 61184 B -> 2 blocks/CU.
// ---------------------------------------------------------------------------
__global__ __launch_bounds__(256) void ka_window(
    const float* __restrict__ x,
    const float* __restrict__ attn_w,
    const float* __restrict__ attn_b,
    __hip_bfloat16* __restrict__ out_pre)
{
    __shared__ __attribute__((aligned(16))) __bf16 xw[80 * 72];    // [row][k] rows 72..79 unused
    __shared__ __attribute__((aligned(16))) __bf16 vS[80 * 200];   // [row][e]
    __shared__ float pooled[8][64];
    __shared__ float attnS[8][488];

    const int tid = threadIdx.x;
    const int lane = tid & 63;
    const int wv = tid >> 6;
    const int m16 = lane & 15;
    const int quad = lane >> 4;
    const int wbase = blockIdx.x * 8;

    // --- Phase 1: load x rows (72 x 64 fp32, coalesced) -> bf16 LDS ---
    #pragma unroll
    for (int it = 0; it < 18; ++it) {
        int t = it * 256 + tid;              // 0..4607
        int row = t >> 6;                    // 0..71 (window-local pixel row)
        int c = t & 63;
        int win = row / 9;
        int q = row - win * 9;
        int widx = wbase + win;
        int b = widx / 5376;
        int rem = widx - b * 5376;
        int i = rem >> 6;
        int j = rem & 63;
        int pr = q / 3;
        int pc = q - pr * 3;
        float xv = x[((b * NH + (i * 3 + pr)) * NW + (j * 3 + pc)) * NC + c];
        xw[row * 72 + c] = (__bf16)xv;
    }
    __syncthreads();

    // --- Phase 1.5: pooled = mean over 9 pixels ---
    #pragma unroll
    for (int it = 0; it < 2; ++it) {
        int t = it * 256 + tid;              // 0..511
        int win = t >> 6;
        int c = t & 63;
        float s = 0.f;
        #pragma unroll
        for (int q = 0; q < 9; ++q) s += bfu2f(xw[(win * 9 + q) * 72 + c]);
        pooled[win][c] = s * (1.f / 9.f);
    }
    __syncthreads();

    // --- Phase 2: logits = (pooled @ attn_w + b) * SCALE ---
    {
        float a0[8], a1[8];
        #pragma unroll
        for (int g = 0; g < 8; ++g) { a0[g] = 0.f; a1[g] = 0.f; }
        const int o0 = tid;
        const int o1 = tid + 256;
        const bool has1 = (o1 < NO);
        for (int c = 0; c < 64; ++c) {
            float w0 = attn_w[c * NO + o0];
            float w1 = has1 ? attn_w[c * NO + o1] : 0.f;
            #pragma unroll
            for (int g = 0; g < 8; ++g) {
                float p = pooled[g][c];
                a0[g] = fmaf(p, w0, a0[g]);
                a1[g] = fmaf(p, w1, a1[g]);
            }
        }
        float b0 = attn_b[o0];
        #pragma unroll
        for (int g = 0; g < 8; ++g) attnS[g][o0] = (a0[g] + b0) * SCALE_F;
        if (has1) {
            float b1 = attn_b[o1];
            #pragma unroll
            for (int g = 0; g < 8; ++g) attnS[g][o1] = (a1[g] + b1) * SCALE_F;
        }
    }
    __syncthreads();

    // --- Phase 3: softmax over groups of 9 ---
    #pragma unroll
    for (int it = 0; it < 2; ++it) {
        int t = it * 256 + tid;
        if (t < 432) {
            int win = t / 54;
            int g = t - win * 54;
            float* a = &attnS[win][g * 9];
            float m = a[0];
            #pragma unroll
            for (int q = 1; q < 9; ++q) m = fmaxf(m, a[q]);
            float e[9];
            float s = 0.f;
            #pragma unroll
            for (int q = 0; q < 9; ++q) { e[q] = __expf(a[q] - m); s += e[q]; }
            float inv = 1.f / s;
            #pragma unroll
            for (int q = 0; q < 9; ++q) a[q] = e[q] * inv;
        }
    }
    __syncthreads();

    // --- Phase 4a: v = xw @ v_w via MFMA.  M=80 (5 mt), N=192 (wave strip 48), K=64 ---
    {
        const __bf16* Bv = (const __bf16*)g_vwT;
        bf16x8 bfragV[2][3];
        #pragma unroll
        for (int ks = 0; ks < 2; ++ks)
            #pragma unroll
            for (int nt = 0; nt < 3; ++nt)
                bfragV[ks][nt] = *(const bf16x8*)(Bv + (wv * 48 + nt * 16 + m16) * 64 + ks * 32 + quad * 8);

        floatx4 acc[5][3];
        #pragma unroll
        for (int mt = 0; mt < 5; ++mt)
            #pragma unroll
            for (int nt = 0; nt < 3; ++nt) {
                acc[mt][nt][0] = 0.f; acc[mt][nt][1] = 0.f;
                acc[mt][nt][2] = 0.f; acc[mt][nt][3] = 0.f;
            }
        #pragma unroll
        for (int ks = 0; ks < 2; ++ks)
            #pragma unroll
            for (int mt = 0; mt < 5; ++mt) {
                bf16x8 afrag = *(const bf16x8*)(&xw[(mt * 16 + m16) * 72 + ks * 32 + quad * 8]);
                #pragma unroll
                for (int nt = 0; nt < 3; ++nt)
                    acc[mt][nt] = __builtin_amdgcn_mfma_f32_16x16x32_bf16(afrag, bfragV[ks][nt], acc[mt][nt], 0, 0, 0);
            }
        // C/D: col=lane&15, row=quad*4+r.  Rows >=72 are padding garbage (never read).
        #pragma unroll
        for (int mt = 0; mt < 5; ++mt)
            #pragma unroll
            for (int nt = 0; nt < 3; ++nt)
                #pragma unroll
                for (int r = 0; r < 4; ++r) {
                    int row = mt * 16 + quad * 4 + r;
                    int col = wv * 48 + nt * 16 + m16;
                    vS[row * 200 + col] = (__bf16)acc[mt][nt][r];
                }
    }
    __syncthreads();

    // --- Phase 4b: out = attn @ v, scatter to out_pre ---
    #pragma unroll
    for (int pass = 0; pass < 2; ++pass) {
        int t = pass * 256 + tid;
        if (t < 384) {
            int win = t / 48;
            int e0 = t - win * 48;
            float v0[9], v1[9], v2[9], v3[9];
            #pragma unroll
            for (int q = 0; q < 9; ++q) {
                const __bf16* vr = &vS[(win * 9 + q) * 200];
                v0[q] = bfu2f(vr[e0]);
                v1[q] = bfu2f(vr[e0 + 48]);
                v2[q] = bfu2f(vr[e0 + 96]);
                v3[q] = bfu2f(vr[e0 + 144]);
            }
            int widx = wbase + win;
            int b = widx / 5376;
            int rem = widx - b * 5376;
            int i = rem >> 6;
            int j = rem & 63;
            const float* at = &attnS[win][0];
            const int h0 = (e0) >> 5;
            const int h1 = (e0 + 48) >> 5;
            const int h2 = (e0 + 96) >> 5;
            const int h3 = (e0 + 144) >> 5;
            #pragma unroll
            for (int p = 0; p < 9; ++p) {
                const float* r0 = at + h0 * 81 + p * 9;
                const float* r1 = at + h1 * 81 + p * 9;
                const float* r2 = at + h2 * 81 + p * 9;
                const float* r3 = at + h3 * 81 + p * 9;
                float o0 = 0.f, o1 = 0.f, o2 = 0.f, o3 = 0.f;
                #pragma unroll
                for (int q = 0; q < 9; ++q) {
                    o0 = fmaf(r0[q], v0[q], o0);
                    o1 = fmaf(r1[q], v1[q], o1);
                    o2 = fmaf(r2[q], v2[q], o2);
                    o3 = fmaf(r3[q], v3[q], o3);
                }
                int pr = p / 3;
                int pc = p - pr * 3;
                int base = ((b * NH + (i * 3 + pr)) * NW + (j * 3 + pc)) * NE;
                out_pre[base + e0]       = __float2bfloat16(o0);
                out_pre[base + e0 + 48]  = __float2bfloat16(o1);
                out_pre[base + e0 + 96]  = __float2bfloat16(o2);
                out_pre[base + e0 + 144] = __float2bfloat16(o3);
            }
        }
    }
}

// ---------------------------------------------------------------------------
// Kernel B: final = out_pre @ out_w + out_b  (M=387072, N=K=192), fp32 out.
// B fragments hoisted to registers ONCE (72 VGPRs); tile loop = ds_read+MFMA.
// ---------------------------------------------------------------------------
__global__ __launch_bounds__(256) void kb_gemm(
    const __hip_bfloat16* __restrict__ Ain,
    const float* __restrict__ out_b,
    float* __restrict__ out)
{
    __shared__ __attribute__((aligned(16))) ushort As[64 * 200];   // [m][k], pad 192->200

    const int tid = threadIdx.x;
    const int lane = tid & 63;
    const int wv = tid >> 6;          // wave -> n-strip [wv*48, wv*48+48)
    const int m16 = lane & 15;
    const int quad = lane >> 4;

    float bias[3];
    #pragma unroll
    for (int nt = 0; nt < 3; ++nt) bias[nt] = out_b[wv * 48 + nt * 16 + m16];

    // Hoist all B fragments for this wave's 48-col strip: identical across tiles.
    const __bf16* Bu = (const __bf16*)g_owT;
    bf16x8 bfragB[6][3];
    #pragma unroll
    for (int ks = 0; ks < 6; ++ks)
        #pragma unroll
        for (int nt = 0; nt < 3; ++nt)
            bfragB[ks][nt] = *(const bf16x8*)(Bu + (wv * 48 + nt * 16 + m16) * 192 + ks * 32 + quad * 8);

    const ushort* Au = (const ushort*)Ain;

    for (int tI = 0; tI < 8; ++tI) {
        int mbase = (blockIdx.x * 8 + tI) * 64;
        __syncthreads();   // As reuse guard
        #pragma unroll
        for (int it = 0; it < 6; ++it) {
            int chunk = it * 256 + tid;      // 1536 chunks of 16B
            int r = chunk / 24;
            int pos = chunk - r * 24;
            uint4 vdat = *(const uint4*)(Au + (mbase + r) * 192 + pos * 8);
            *(uint4*)(&As[r * 200 + pos * 8]) = vdat;
        }
        __syncthreads();

        floatx4 acc[4][3];
        #pragma unroll
        for (int mt = 0; mt < 4; ++mt)
            #pragma unroll
            for (int nt = 0; nt < 3; ++nt) {
                acc[mt][nt][0] = 0.f; acc[mt][nt][1] = 0.f;
                acc[mt][nt][2] = 0.f; acc[mt][nt][3] = 0.f;
            }

        #pragma unroll
        for (int ks = 0; ks < 6; ++ks)
            #pragma unroll
            for (int mt = 0; mt < 4; ++mt) {
                bf16x8 afrag = *(const bf16x8*)(&As[(mt * 16 + m16) * 200 + ks * 32 + quad * 8]);
                #pragma unroll
                for (int nt = 0; nt < 3; ++nt)
                    acc[mt][nt] = __builtin_amdgcn_mfma_f32_16x16x32_bf16(afrag, bfragB[ks][nt], acc[mt][nt], 0, 0, 0);
            }

        // Epilogue: C/D col=lane&15, row=quad*4+r; fp32 stores.
        #pragma unroll
        for (int mt = 0; mt < 4; ++mt)
            #pragma unroll
            for (int nt = 0; nt < 3; ++nt)
                #pragma unroll
                for (int r = 0; r < 4; ++r) {
                    int row = mbase + mt * 16 + quad * 4 + r;
                    int col = wv * 48 + nt * 16 + m16;
                    out[row * NE + col] = acc[mt][nt][r] + bias[nt];
                }
    }
}

extern "C" void kernel_launch(void* const* d_in, const int* in_sizes, int n_in,
                              void* d_out, int out_size, void* d_ws, size_t ws_size,
                              hipStream_t stream)
{
    const float* x      = (const float*)d_in[0];
    const float* v_w    = (const float*)d_in[1];
    const float* attn_w = (const float*)d_in[2];
    const float* attn_b = (const float*)d_in[3];
    const float* out_w  = (const float*)d_in[4];
    const float* out_b  = (const float*)d_in[5];
    float* out = (float*)d_out;

    __hip_bfloat16* out_pre = (__hip_bfloat16*)d_ws;  // 148,635,648 B

    hipLaunchKernelGGL(kt_transpose, dim3(192), dim3(256), 0, stream, out_w, v_w);
    hipLaunchKernelGGL(ka_window, dim3(NWIN / 8), dim3(256), 0, stream,
                       x, attn_w, attn_b, out_pre);
    hipLaunchKernelGGL(kb_gemm, dim3(NM / 64 / 8), dim3(256), 0, stream,
                       out_pre, out_b, out);
}